// Round 14
// baseline (223.877 us; speedup 1.0000x reference)
//
#include <hip/hip_runtime.h>
#include <hip/hip_bf16.h>
#include <stdint.h>

#define N_ROWS 8192
#define DIM    1024
#define BM 128
#define BN 128
#define BKF 64             // fp8 bytes of K per slice (= one MFMA32 K)
#define NSL 16             // K-slices per C-tile (1024/64)
#define TILES_PB 4         // B-tiles per block (F-amortization)
#define VSTEPS (NSL * TILES_PB)   // 64 virtual K-steps per block
#define BUFSZ 16384u       // A 8K + B 8K per slice buffer; dbuf = 32 KiB

typedef float   f32x4   __attribute__((ext_vector_type(4)));
typedef float   f32x16  __attribute__((ext_vector_type(16)));
typedef int     i32x4   __attribute__((ext_vector_type(4)));
typedef int     i32x8   __attribute__((ext_vector_type(8)));

// 16-lane (DPP row) cyclic all-reduce sum — no LDS traffic.
__device__ __forceinline__ float row_sum16(float x) {
    x += __int_as_float(__builtin_amdgcn_update_dpp(
            0, __float_as_int(x), 0x128 /*row_ror:8*/, 0xf, 0xf, true));
    x += __int_as_float(__builtin_amdgcn_update_dpp(
            0, __float_as_int(x), 0x124 /*row_ror:4*/, 0xf, 0xf, true));
    x += __int_as_float(__builtin_amdgcn_update_dpp(
            0, __float_as_int(x), 0x122 /*row_ror:2*/, 0xf, 0xf, true));
    x += __int_as_float(__builtin_amdgcn_update_dpp(
            0, __float_as_int(x), 0x121 /*row_ror:1*/, 0xf, 0xf, true));
    return x;
}

// ---------------------------------------------------------------------------
// Kernel 1: L2-normalize + fp8 cast + diagonal + S init.  UNCHANGED.
// ---------------------------------------------------------------------------
__global__ __launch_bounds__(256) void nrm_kernel(
    const float* __restrict__ img, const float* __restrict__ txt,
    uint8_t* __restrict__ img_f8, uint8_t* __restrict__ txt_f8,
    float* __restrict__ diag, float* __restrict__ S)
{
    const int t    = threadIdx.x;
    const int lane = t & 63;
    const int wv   = t >> 6;
    const int row  = blockIdx.x * 4 + wv;

    const float4* ip = (const float4*)(img + (size_t)row * DIM);
    const float4* tp = (const float4*)(txt + (size_t)row * DIM);

    float4 a[4], b[4];
    float sa = 0.f, sb = 0.f, dp = 0.f;
#pragma unroll
    for (int j = 0; j < 4; ++j) {
        a[j] = ip[lane + 64 * j];
        b[j] = tp[lane + 64 * j];
        sa += a[j].x * a[j].x + a[j].y * a[j].y + a[j].z * a[j].z + a[j].w * a[j].w;
        sb += b[j].x * b[j].x + b[j].y * b[j].y + b[j].z * b[j].z + b[j].w * b[j].w;
        dp += a[j].x * b[j].x + a[j].y * b[j].y + a[j].z * b[j].z + a[j].w * b[j].w;
    }
#pragma unroll
    for (int d = 1; d < 64; d <<= 1) {
        sa += __shfl_xor(sa, d, 64);
        sb += __shfl_xor(sb, d, 64);
        dp += __shfl_xor(dp, d, 64);
    }

    const float ia = 1.0f / fmaxf(sqrtf(sa), 1e-12f);
    const float ib = 1.0f / fmaxf(sqrtf(sb), 1e-12f);

#pragma unroll
    for (int j = 0; j < 4; ++j) {
        int ra = 0, rb = 0;
        ra = __builtin_amdgcn_cvt_pk_fp8_f32(a[j].x * ia, a[j].y * ia, ra, false);
        ra = __builtin_amdgcn_cvt_pk_fp8_f32(a[j].z * ia, a[j].w * ia, ra, true);
        rb = __builtin_amdgcn_cvt_pk_fp8_f32(b[j].x * ib, b[j].y * ib, rb, false);
        rb = __builtin_amdgcn_cvt_pk_fp8_f32(b[j].z * ib, b[j].w * ib, rb, true);
        ((int*)(img_f8 + (size_t)row * DIM))[lane + 64 * j] = ra;
        ((int*)(txt_f8 + (size_t)row * DIM))[lane + 64 * j] = rb;
    }

    if (lane == 0) {
        diag[row] = dp * ia * ib;
        S[row] = 0.0f;
    }
}

// ---------------------------------------------------------------------------
// Kernel 2: 128x128 MX-fp8 GEMM with 32x32x64 MFMA (K=64 slices).
//   R13 analysis: LDS-read pipe ~67% busy; reads/work scale as 2(mi+ni)/mi*ni
//   so only BIGGER wave tiles cut LDS traffic, and K=64 slices make the
//   buffers thin enough (A 8K + B 8K, dbuf 32 KiB) to keep 4 blocks/CU.
//   4 waves (2x2) of 64x64 = 2x2 mfma_scale_f32_32x32x64_f8f6f4 per slice;
//   acc[2][2] f32x16 (64 VGPR); 8 ds_read_b128 per wave-slice for 4 MFMA32
//   (1:1 read:MFMA16-equiv, R12's ratio) at R13-class occupancy.
//   LDS layout: row pairs form 128B "vrows"; chunk vc of vrow stored at
//   vc ^ (vrow&7) (same verified XOR idiom, applied via permuted global
//   source).  Read side: lane l reads row (l&31) k-half (l>>5): lo/hi remain
//   the adr / adr^16 pair; mi/ni fold into imm (mi*2048).
//   A/B fragment layout by exact analogy to the verified 16x16x128 kernel
//   (row = lane&31, k = (lane>>5)*32).  C/D: col=lane&31,
//   row=(reg&3)+8*(reg>>2)+4*(lane>>5)  [m74/m101].
//   Skeleton: R12/R13's verified 2-sub-step pair loop, TILES_PB=4 (vsteps=64,
//   same F-amortization), grid 16 B-groups x 64 A-panels = 1024 blocks.
//   Epilogue per tile-finish (p&7==7): sum ni-pair post-exp2, row_sum16 DPP
//   + one shfl_xor(16) per reg, atomics from lanes 0/32.
// ---------------------------------------------------------------------------
__global__ __launch_bounds__(256) void sim_lse_kernel(
    const uint8_t* __restrict__ A, const uint8_t* __restrict__ B,
    float* __restrict__ S)
{
    __shared__ __align__(16) uint8_t smem[2 * BUFSZ];   // 32 KiB

    const int t     = threadIdx.x;       // 0..255
    const int lane  = t & 63;
    const int w     = t >> 6;            // wave 0..3
    const int waveM = w >> 1;            // 2x2 wave grid, 64x64 each
    const int waveN = w & 1;
    const int l31   = lane & 31;

    const int rowA0 = blockIdx.y * BM;                    // A panel (0..63)
    const uint8_t* Ablk = A + (size_t)rowA0 * DIM;
    const uint8_t* Bgrp = B + (size_t)blockIdx.x * TILES_PB * BN * DIM;

    // ---- staging: 256 threads x (2 A + 2 B) 16B chunks --------------------
    // LDS slot cc*16 (lane-linear dest); slot cc holds (vrow=cc>>3,
    // vc=(cc&7)^(vrow&7)) -> row = vrow*2 + (vc>>2), chunk c = vc&3.
    const uint8_t* pA[2];
    const uint8_t* pB[2];
    uint32_t ldsA[2], ldsB[2];
#pragma unroll
    for (int is = 0; is < 2; ++is) {
        const int cc   = is * 256 + t;       // 0..511
        const int vrow = cc >> 3;            // 0..63 (row pairs)
        const int vc   = (cc & 7) ^ (vrow & 7);
        const int row  = vrow * 2 + (vc >> 2);   // 0..127
        const int c    = vc & 3;                 // 16B chunk within 64B row
        pA[is] = Ablk + (size_t)row * DIM + c * 16;
        pB[is] = Bgrp + (size_t)row * DIM + c * 16;
        ldsA[is] = (uint32_t)cc * 16;
        ldsB[is] = 8192u + (uint32_t)cc * 16;
    }

    auto stage_inc = [&](uint32_t ldsbase) {
#pragma unroll
        for (int is = 0; is < 2; ++is) {
            __builtin_amdgcn_global_load_lds(
                (const __attribute__((address_space(1))) void*)pA[is],
                (__attribute__((address_space(3))) void*)&smem[ldsbase + ldsA[is]],
                16, 0, 0);
            __builtin_amdgcn_global_load_lds(
                (const __attribute__((address_space(1))) void*)pB[is],
                (__attribute__((address_space(3))) void*)&smem[ldsbase + ldsB[is]],
                16, 0, 0);
        }
    };

    // ---- per-lane ds_read base addresses ----------------------------------
    // lane reads row (base + l&31), k-bytes (l>>5)*32..+31 = chunks {2h,2h+1}
    // vrow = row>>1 -> key=(l>>1)&7 (mi*16 vrows offset doesn't touch key);
    // vchunk0 = (l&1)*4 + 2h (even) -> hi slot = lo ^ 16.
    const uint32_t rkey = (uint32_t)((lane >> 1) & 7);
    const uint32_t vch0 = (uint32_t)((lane & 1) * 4 + 2 * (lane >> 5));
    const uint32_t swzc = (vch0 ^ rkey) * 16;
    const uint32_t adrA  = (uint32_t)((waveM * 32 + (l31 >> 1)) * 128) + swzc;
    const uint32_t adrAh = adrA ^ 16u;
    const uint32_t adrB  = 8192u + (uint32_t)((waveN * 32 + (l31 >> 1)) * 128) + swzc;
    const uint32_t adrBh = adrB ^ 16u;

    f32x16 acc[2][2];
#pragma unroll
    for (int mi = 0; mi < 2; ++mi)
#pragma unroll
        for (int ni = 0; ni < 2; ++ni)
#pragma unroll
            for (int r = 0; r < 16; ++r) acc[mi][ni][r] = 0.f;

    // ---- prologue: stage slice 0 into buf0, advance, drain once -----------
    stage_inc(0u);
#pragma unroll
    for (int is = 0; is < 2; ++is) { pA[is] += BKF; pB[is] += BKF; }
    asm volatile("s_waitcnt vmcnt(0)" ::: "memory");
    __builtin_amdgcn_s_barrier();

    const float L2E = 1.44269504088896f;
    const int rowbase = rowA0 + waveM * 64;

    // compute one K=64 slice from buffer RBUF (compile-time 0 / 16384)
    auto compute = [&](uint32_t RBUF) {
        i32x8 af[2], bf[2];
#pragma unroll
        for (int mi = 0; mi < 2; ++mi) {
            i32x4 lo = *(const i32x4*)&smem[adrA  + RBUF + mi * 2048];
            i32x4 hi = *(const i32x4*)&smem[adrAh + RBUF + mi * 2048];
            af[mi] = __builtin_shufflevector(lo, hi, 0, 1, 2, 3, 4, 5, 6, 7);
        }
#pragma unroll
        for (int ni = 0; ni < 2; ++ni) {
            i32x4 lo = *(const i32x4*)&smem[adrB  + RBUF + ni * 2048];
            i32x4 hi = *(const i32x4*)&smem[adrBh + RBUF + ni * 2048];
            bf[ni] = __builtin_shufflevector(lo, hi, 0, 1, 2, 3, 4, 5, 6, 7);
        }
#pragma unroll
        for (int mi = 0; mi < 2; ++mi)
#pragma unroll
            for (int ni = 0; ni < 2; ++ni)
                acc[mi][ni] = __builtin_amdgcn_mfma_scale_f32_32x32x64_f8f6f4(
                    af[mi], bf[ni], acc[mi][ni],
                    0 /*fmtA=fp8*/, 0 /*fmtB=fp8*/,
                    0, 127 /*scaleA=1.0*/, 0, 127 /*scaleB=1.0*/);
    };

    // ---- main loop: 32 pairs; buffer parity compile-time per sub-step -----
#pragma unroll 1
    for (int p = 0; p < VSTEPS / 2; ++p) {
        // ===== sub-step A: v = 2p (even). read buf0, stage buf1 ===========
        stage_inc(BUFSZ);                          // stage v+1 (2p < 63)
        {
            // advance to v+2 data; wrap iff (2p+1)%16==15 <=> (p&7)==7
            const bool wrap = (p & 7) == 7;
            const int dA = wrap ? -(BKF * (NSL - 1)) : BKF;              // -960 | +64
            const int dB = wrap ? (BN * DIM - BKF * (NSL - 1)) : BKF;    // +130112 | +64
#pragma unroll
            for (int is = 0; is < 2; ++is) { pA[is] += dA; pB[is] += dB; }
        }
        compute(0u);
        asm volatile("s_waitcnt vmcnt(0)" ::: "memory");
        __builtin_amdgcn_s_barrier();

        // ===== sub-step B: v = 2p+1 (odd). read buf1, stage buf0 ==========
        if (p < VSTEPS / 2 - 1) {
            stage_inc(0u);                         // stage v+1
            // wrap impossible at odd v+1: unconditional +64
#pragma unroll
            for (int is = 0; is < 2; ++is) { pA[is] += BKF; pB[is] += BKF; }
        }
        compute(BUFSZ);

        if ((p & 7) == 7) {   // v%16==15: C-tile finished -> fused epilogue
#pragma unroll
            for (int mi = 0; mi < 2; ++mi) {
#pragma unroll
                for (int r = 0; r < 16; ++r) {
                    float e = exp2f(acc[mi][0][r] * L2E - L2E)
                            + exp2f(acc[mi][1][r] * L2E - L2E);
                    e = row_sum16(e);          // sum within 16-lane DPP row
                    e += __shfl_xor(e, 16, 64);// combine the two 16-groups
                    if (l31 == 0) {
                        // C/D: row = (r&3) + 8*(r>>2) + 4*(lane>>5)
                        atomicAdd(&S[rowbase + mi * 32 + (r & 3) + 8 * (r >> 2)
                                     + 4 * (lane >> 5)], e);
                    }
                }
#pragma unroll
                for (int ni = 0; ni < 2; ++ni)
#pragma unroll
                    for (int r = 0; r < 16; ++r) acc[mi][ni][r] = 0.f;
            }
        }

        asm volatile("s_waitcnt vmcnt(0)" ::: "memory");
        __builtin_amdgcn_s_barrier();
    }
}

// ---------------------------------------------------------------------------
// Kernel 3: out = mean(log(S_i) - diag_i)   UNCHANGED
// ---------------------------------------------------------------------------
__global__ __launch_bounds__(1024) void fin_kernel(
    const float* __restrict__ S, const float* __restrict__ diag,
    float* __restrict__ out)
{
    const int t = threadIdx.x;
    float s = 0.f;
    for (int i = t; i < N_ROWS; i += 1024) s += logf(S[i]) - diag[i];
#pragma unroll
    for (int d = 1; d < 64; d <<= 1) s += __shfl_xor(s, d, 64);
    __shared__ float red[16];
    if ((t & 63) == 0) red[t >> 6] = s;
    __syncthreads();
    if (t == 0) {
        float tot = 0.f;
#pragma unroll
        for (int i = 0; i < 16; ++i) tot += red[i];
        out[0] = tot * (1.0f / N_ROWS);
    }
}

// ---------------------------------------------------------------------------
extern "C" void kernel_launch(void* const* d_in, const int* in_sizes, int n_in,
                              void* d_out, int out_size, void* d_ws, size_t ws_size,
                              hipStream_t stream)
{
    const float* img = (const float*)d_in[0];
    const float* txt = (const float*)d_in[1];
    float* out = (float*)d_out;

    char* ws = (char*)d_ws;
    uint8_t* img_f8 = (uint8_t*)ws;                                  // 8 MiB
    uint8_t* txt_f8 = (uint8_t*)(ws + (size_t)N_ROWS * DIM);         // 8 MiB
    float*   S      = (float*)(ws + (size_t)N_ROWS * DIM * 2);       // 32 KiB
    float*   diag   = S + N_ROWS;                                    // 32 KiB

    nrm_kernel<<<N_ROWS / 4, 256, 0, stream>>>(img, txt, img_f8, txt_f8,
                                               diag, S);
    dim3 grid(N_ROWS / BN / TILES_PB, N_ROWS / BM);   // 16 groups x 64 panels
    sim_lse_kernel<<<grid, 256, 0, stream>>>(img_f8, txt_f8, S);
    fin_kernel<<<1, 1024, 0, stream>>>(S, diag, out);
}